// Round 10
// baseline (266.287 us; speedup 1.0000x reference)
//
#include <hip/hip_runtime.h>
#include <hip/hip_bf16.h>

typedef __hip_bfloat16 bf16;
typedef __attribute__((ext_vector_type(8))) short short8;
typedef __attribute__((ext_vector_type(4))) short short4v;
typedef __attribute__((ext_vector_type(4))) float floatx4;

static constexpr int B = 4;
static constexpr int N = 2048;
static constexpr int C = 512;
static constexpr int H = 8;
static constexpr int D = 64;

// 0.125 * log2(e): folded into q so flash can use native exp2.
#define QK_SCALE 0.18033688011112042f

// Per-input dtype flags: 0 = bf16, 1 = fp32, 2 = all-zero tensor.
__device__ int g_flags[18];

__device__ __forceinline__ float u2f(unsigned short u) {
    return __uint_as_float(((unsigned int)u) << 16);
}
__device__ __forceinline__ unsigned short f2bf(float f) {  // RNE
    unsigned int u = __float_as_uint(f);
    return (unsigned short)((u + 0x7FFFu + ((u >> 16) & 1u)) >> 16);
}
__device__ __forceinline__ float ldin(const void* p, size_t i, int f) {
    if (f == 2) return 0.0f;
    return f ? ((const float*)p)[i] : u2f(((const unsigned short*)p)[i]);
}

// Load 8 consecutive floats starting at element idx, honoring dtype flag.
__device__ __forceinline__ void ld8(const void* p, size_t idx, int f, float* o) {
    if (f == 1) {
        const float4* q = (const float4*)((const float*)p + idx);
        float4 a = q[0], b2 = q[1];
        o[0] = a.x; o[1] = a.y; o[2] = a.z; o[3] = a.w;
        o[4] = b2.x; o[5] = b2.y; o[6] = b2.z; o[7] = b2.w;
    } else if (f == 0) {
        short8 s8 = *(const short8*)((const unsigned short*)p + idx);
        #pragma unroll
        for (int i = 0; i < 8; ++i) o[i] = u2f((unsigned short)s8[i]);
    } else {
        #pragma unroll
        for (int i = 0; i < 8; ++i) o[i] = 0.0f;
    }
}

// Async global->LDS DMA, 16B per lane. LDS dest is wave-uniform base +
// lane*16 (lane0's pointer value is the base).
__device__ __forceinline__ void gl_lds16(const unsigned short* g, unsigned short* l) {
    __builtin_amdgcn_global_load_lds(
        (const __attribute__((address_space(1))) unsigned int*)g,
        (__attribute__((address_space(3))) unsigned int*)l,
        16, 0, 0);
}

struct Ptrs { const void* p[18]; };

__global__ void detect_kernel(Ptrs ptrs) {
    int t = blockIdx.x;
    int lane = threadIdx.x;  // 64
    unsigned int v = ((const unsigned int*)ptrs.p[t])[lane];
    unsigned int e = (v >> 7) & 0xFF;
    unsigned long long mp = __ballot(e >= 96 && e <= 144);
    unsigned long long mz = __ballot(v != 0u);
    if (lane == 0)
        g_flags[t] = (mz == 0ull) ? 2 : ((__popcll(mp) >= 32) ? 0 : 1);
}

// ---------------------------------------------------------------------------
// One-shot weight conversion: all 6 W matrices (512x512) -> bf16 workspace.
// ---------------------------------------------------------------------------
__global__ __launch_bounds__(256) void convert_w(Ptrs ptrs, bf16* dst) {
    int wsel = blockIdx.y;
    int wi = wsel < 4 ? 2 + 2 * wsel : 14 + 2 * (wsel - 4);  // Wq,Wk,Wvr,Wvd,Wpr,Wpd
    int f = g_flags[wi];
    const void* src = ptrs.p[wi];
    unsigned short* out = (unsigned short*)dst + (size_t)wsel * 262144;
    int base = (blockIdx.x * 256 + threadIdx.x) * 16;
    if (f == 1) {
        const float4* s = (const float4*)((const float*)src + base);
        float4 f0 = s[0], f1 = s[1], f2 = s[2], f3 = s[3];
        uint4 o0, o1;
        o0.x = f2bf(f0.x) | ((unsigned int)f2bf(f0.y) << 16);
        o0.y = f2bf(f0.z) | ((unsigned int)f2bf(f0.w) << 16);
        o0.z = f2bf(f1.x) | ((unsigned int)f2bf(f1.y) << 16);
        o0.w = f2bf(f1.z) | ((unsigned int)f2bf(f1.w) << 16);
        o1.x = f2bf(f2.x) | ((unsigned int)f2bf(f2.y) << 16);
        o1.y = f2bf(f2.z) | ((unsigned int)f2bf(f2.w) << 16);
        o1.z = f2bf(f3.x) | ((unsigned int)f2bf(f3.y) << 16);
        o1.w = f2bf(f3.z) | ((unsigned int)f2bf(f3.w) << 16);
        *(uint4*)(out + base) = o0;
        *(uint4*)(out + base + 8) = o1;
    } else if (f == 0) {
        const uint4* s = (const uint4*)((const unsigned short*)src + base);
        uint4 a = s[0], b2 = s[1];
        *(uint4*)(out + base) = a;
        *(uint4*)(out + base + 8) = b2;
    } else {
        uint4 z = {0, 0, 0, 0};
        *(uint4*)(out + base) = z;
        *(uint4*)(out + base + 8) = z;
    }
}

// ---------------------------------------------------------------------------
// LayerNorm v2: ONE WAVE PER ROW. 64 lanes x 8 ch, butterfly shfl reduce,
// no LDS, no barriers, fully vectorized loads/stores. 4 rows per block.
// ---------------------------------------------------------------------------
__global__ __launch_bounds__(256) void ln_kernel(
    const void* __restrict__ x, const void* __restrict__ y,
    const void* __restrict__ g_r, const void* __restrict__ b_r,
    const void* __restrict__ g_d, const void* __restrict__ b_d,
    bf16* __restrict__ xn, bf16* __restrict__ yn)
{
    int tid = threadIdx.x;
    int wid = tid >> 6, lane = tid & 63;
    int row = blockIdx.x * 4 + wid;
    bool isY = row >= B * N;
    int r = isY ? row - B * N : row;
    const void* src = isY ? y : x;
    int sf = isY ? g_flags[1] : g_flags[0];
    const void* g  = isY ? g_d : g_r;
    int gf = isY ? g_flags[12] : g_flags[10];
    const void* bb = isY ? b_d : b_r;
    int bflag = isY ? g_flags[13] : g_flags[11];
    bf16* dst = (isY ? yn : xn) + (size_t)r * C;

    int col = lane * 8;
    float v[8];
    ld8(src, (size_t)r * C + col, sf, v);

    float s = 0.f, sq = 0.f;
    #pragma unroll
    for (int i = 0; i < 8; ++i) { s += v[i]; sq += v[i] * v[i]; }
    #pragma unroll
    for (int off = 1; off < 64; off <<= 1) {
        s  += __shfl_xor(s, off);
        sq += __shfl_xor(sq, off);
    }
    float mu = s * (1.0f / C);
    float var = sq * (1.0f / C) - mu * mu;
    float rs = rsqrtf(var + 1e-5f);

    float gv[8], bv[8];
    ld8(g, col, gf, gv);
    ld8(bb, col, bflag, bv);

    union { unsigned short us[8]; short8 s8; } o;
    #pragma unroll
    for (int i = 0; i < 8; ++i)
        o.us[i] = f2bf((v[i] - mu) * rs * gv[i] + bv[i]);
    *(short8*)(dst + col) = o.s8;
}

// ---------------------------------------------------------------------------
// MFMA GEMM core v4: 128x128 block tile, 64x64 wave tile, BK=32 windows,
// FOUR LDS buffers (64KB), prefetch distance 3 with COUNTED vmcnt(8) --
// loads never drain to 0 in the main loop, so ~900cy HBM latency spans
// 3 windows of compute instead of being exposed per window (the exposed
// drain was the ~20us/GEMM ceiling of v1..v3).
// Race-free: every wave's vmcnt(8) before the barrier implies its own
// window-w chunks landed (only w+1,w+2 remain in flight); the barrier
// orders buffer reuse (buf of w+3 was last read in window w-1).
// 4-seg XOR swizzle (seg' = seg ^ (row&3)) keeps ds_read_b128 conflict-free.
// omode 0: bf16 row-major; 1: fp32 row-major; 2: bf16 transposed per-batch.
// ---------------------------------------------------------------------------
__device__ __forceinline__ void gemm_core(
    const bf16* __restrict__ A, const bf16* __restrict__ W,
    const void* __restrict__ bias, int bflag, void* __restrict__ Cout,
    int omode, float oscale, int n0, int m0)
{
    __shared__ __align__(16) unsigned short As[4][128 * 32];
    __shared__ __align__(16) unsigned short Ws[4][128 * 32];

    int tid = threadIdx.x;
    int wave = tid >> 6, lane = tid & 63;
    int wm = (wave >> 1) * 64, wn = (wave & 1) * 64;
    int quad = lane >> 4, mr = lane & 15;

    floatx4 acc[4][4] = {};

    // Window tile = 128 rows x 32 shorts (4 segs of 16B) = 512 chunks per
    // array; 2 per thread. LDS slot (row, s) receives global seg s^(row&3).
    const unsigned short* Asrc[2];
    const unsigned short* Wsrc[2];
    #pragma unroll
    for (int i = 0; i < 2; ++i) {
        int c = i * 256 + tid, row = c >> 2, sg = c & 3;
        Asrc[i] = (const unsigned short*)A + (size_t)(m0 + row) * 512 + ((sg ^ (row & 3)) << 3);
        Wsrc[i] = (const unsigned short*)W + (size_t)(n0 + row) * 512 + ((sg ^ (row & 3)) << 3);
    }

    auto STAGE = [&](int w, int bsel) {
        int ko = w * 32;  // shorts; <= 960B -> folds into imm offset
        #pragma unroll
        for (int i = 0; i < 2; ++i) {
            gl_lds16(Asrc[i] + ko, &As[bsel][(i * 256 + tid) * 8]);
            gl_lds16(Wsrc[i] + ko, &Ws[bsel][(i * 256 + tid) * 8]);
        }
    };

    auto WBODY = [&](int bsel, int w) {   // bsel, w always literals
        // outstanding at entry: {w, w+1, w+2} = 12 loads -> wait to 8 => w done
        if (w < 14) {
            asm volatile("s_waitcnt vmcnt(8)" ::: "memory");
        } else if (w == 14) {
            asm volatile("s_waitcnt vmcnt(4)" ::: "memory");
        } else {
            asm volatile("s_waitcnt vmcnt(0)" ::: "memory");
        }
        __builtin_amdgcn_s_barrier();     // all waves' w-chunks in LDS
        if (w < 13)
            STAGE(w + 3, (w + 3) & 3);
        __builtin_amdgcn_sched_barrier(0);

        int sl = (quad ^ (mr & 3)) << 3;
        short8 af[4], bfr[4];
        #pragma unroll
        for (int i = 0; i < 4; ++i)
            af[i] = *(const short8*)&As[bsel][(wm + i * 16 + mr) * 32 + sl];
        #pragma unroll
        for (int j = 0; j < 4; ++j)
            bfr[j] = *(const short8*)&Ws[bsel][(wn + j * 16 + mr) * 32 + sl];
        #pragma unroll
        for (int i = 0; i < 4; ++i)
            #pragma unroll
            for (int j = 0; j < 4; ++j)
                acc[i][j] = __builtin_amdgcn_mfma_f32_16x16x32_bf16(
                    af[i], bfr[j], acc[i][j], 0, 0, 0);
        __builtin_amdgcn_sched_barrier(0);
    };

    STAGE(0, 0);
    STAGE(1, 1);
    STAGE(2, 2);
    #pragma unroll
    for (int g = 0; g < 4; ++g) {
        WBODY(0, 4 * g);
        WBODY(1, 4 * g + 1);
        WBODY(2, 4 * g + 2);
        WBODY(3, 4 * g + 3);
    }

    float bv[4];
    #pragma unroll
    for (int j = 0; j < 4; ++j)
        bv[j] = ldin(bias, n0 + wn + j * 16 + mr, bflag);
    #pragma unroll
    for (int i = 0; i < 4; ++i) {
        #pragma unroll
        for (int j = 0; j < 4; ++j) {
            int o = n0 + wn + j * 16 + mr;
            #pragma unroll
            for (int reg = 0; reg < 4; ++reg) {
                int r = m0 + wm + i * 16 + quad * 4 + reg;
                float val = (acc[i][j][reg] + bv[j]) * oscale;
                if (omode == 0) {
                    ((bf16*)Cout)[(size_t)r * 512 + o] = __float2bfloat16(val);
                } else if (omode == 1) {
                    ((float*)Cout)[(size_t)r * 512 + o] = val;
                } else {
                    int batch = r >> 11, nn = r & 2047;
                    ((bf16*)Cout)[((size_t)(batch * 512 + o)) * 2048 + nn] =
                        __float2bfloat16(val);
                }
            }
        }
    }
}

// XCD decode for grid (4, 64, z): linear id = bx + 4*by (+256*z) -> XCD =
// id&7. Give each XCD a contiguous band of 8 m-panels (all 4 n-tiles each):
// A working set 1MB/XCD (L2-fits), W 0.5MB.
__device__ __forceinline__ void swz_nm(int& n0, int& m0) {
    int lid = blockIdx.x + 4 * blockIdx.y;   // 0..255 within z-slab
    int xcd = lid & 7;
    int grp = lid >> 3;                      // 0..31
    m0 = (xcd * 8 + (grp >> 2)) * 128;
    n0 = (grp & 3) * 128;
}

// 4 staging GEMMs in one dispatch: z = {q, k, vrT, vdT}
__global__ __launch_bounds__(256, 2) void gemm_stage(
    const bf16* __restrict__ xn, const bf16* __restrict__ yn,
    const bf16* __restrict__ wts, Ptrs ptrs,
    bf16* __restrict__ q, bf16* __restrict__ k,
    bf16* __restrict__ vrT, bf16* __restrict__ vdT)
{
    int z = blockIdx.z;
    const bf16* A = (z == 0) ? yn : xn;
    const bf16* W = wts + (size_t)z * 262144;
    int bi = 3 + 2 * z;
    void* Cout = (z == 0) ? (void*)q : (z == 1) ? (void*)k
               : (z == 2) ? (void*)vrT : (void*)vdT;
    int omode = (z < 2) ? 0 : 2;
    float oscale = (z == 0) ? QK_SCALE : 1.0f;
    int n0, m0;
    swz_nm(n0, m0);
    gemm_core(A, W, ptrs.p[bi], g_flags[bi], Cout, omode, oscale, n0, m0);
}

// 2 output projections in one dispatch
__global__ __launch_bounds__(256, 2) void gemm_out(
    const bf16* __restrict__ Or, const bf16* __restrict__ Ad,
    const bf16* __restrict__ wts, Ptrs ptrs,
    float* __restrict__ out0, float* __restrict__ out1)
{
    int z = blockIdx.z;
    const bf16* A = z ? Ad : Or;
    const bf16* W = wts + (size_t)(4 + z) * 262144;
    int bi = 15 + 2 * z;
    int n0, m0;
    swz_nm(n0, m0);
    gemm_core(A, W, ptrs.p[bi], g_flags[bi], z ? (void*)out1 : (void*)out0,
              1, 1.0f, n0, m0);
}

// ---------------------------------------------------------------------------
// MFMA flash attention v7 (UNCHANGED from R9): 32 Q-rows per wave (two
// 16-row groups sharing every K/V fragment read). 8-wave blocks, 256
// q-rows/block, grid 512 (2 blocks/CU). Swapped-QK^T; P in registers;
// row-sums via ones-MFMA. vmcnt(0) -> barrier -> STAGE(next) -> compute.
// ---------------------------------------------------------------------------
__global__ __launch_bounds__(512, 4) void flash_mfma(
    const bf16* __restrict__ qm, const bf16* __restrict__ km,
    const bf16* __restrict__ vrT, const bf16* __restrict__ vdT,
    bf16* __restrict__ Or, bf16* __restrict__ Ad)
{
    __shared__ __align__(16) unsigned short Ks[2][64 * 64];
    __shared__ __align__(16) unsigned short Vs[2][64 * 64];   // V^T tile [d][kcol]

    // bijective swizzle: phys = [grp:3][qblk:3][xcd:3] -> group = grp<<3|xcd
    int phys = blockIdx.x + 8 * blockIdx.y + 64 * blockIdx.z;
    int s = phys >> 3;
    int qblk = s & 7;
    int gidx = (phys & 7) | ((s >> 3) << 3);
    int pass = gidx >> 5;
    int b = (gidx >> 3) & 3;
    int h = gidx & 7;

    const bf16* Q  = pass ? km : qm;
    const bf16* K  = pass ? qm : km;
    const bf16* Vt = pass ? vdT : vrT;
    bf16* Out = pass ? Ad : Or;

    int tid = threadIdx.x;
    int wave = tid >> 6, lane = tid & 63;
    int quad = lane >> 4, mr = lane & 15;
    int m8 = mr & 7;
    int qw = qblk * 256 + wave * 16;   // group 0; group 1 = qw + 128

    // Q fragments for both row groups: B-operand (n=q-row=mr, c=quad*8+j)
    const unsigned short* Qb0 = (const unsigned short*)Q + ((size_t)(b * N + qw + mr)) * C + h * D;
    const unsigned short* Qb1 = Qb0 + (size_t)128 * C;
    short8 qa0 = *(const short8*)(Qb0 + quad * 8);
    short8 qa1 = *(const short8*)(Qb0 + 32 + quad * 8);
    short8 qb0 = *(const short8*)(Qb1 + quad * 8);
    short8 qb1 = *(const short8*)(Qb1 + 32 + quad * 8);

    floatx4 OaccA[4] = {};
    floatx4 OaccB[4] = {};
    floatx4 la = {}, lb = {};

    short4v ones;
    {
        union { unsigned int u[2]; short4v s4; } cv;
        cv.u[0] = 0x3F803F80u; cv.u[1] = 0x3F803F80u;  // 4x bf16 1.0
        ones = cv.s4;
    }

    // DMA staging: 512 chunks (16B) per tile per array; 1 K + 1 V per thread.
    // LDS slot (row, cs) holds data chunk (row, cs ^ (row&7)).
    int r0 = tid >> 3, cs0 = tid & 7;
    const unsigned short* Kb  = (const unsigned short*)K + ((size_t)b * N) * C + h * D;
    const unsigned short* Vtb = (const unsigned short*)Vt + ((size_t)(b * 512 + h * 64)) * 2048;
    const unsigned short* sk0 = Kb + (size_t)r0 * C + ((cs0 ^ (r0 & 7)) << 3);
    const unsigned short* sv0 = Vtb + (size_t)r0 * 2048 + ((cs0 ^ (r0 & 7)) << 3);

    auto STAGE = [&](int bsel) {
        gl_lds16(sk0, &Ks[bsel][tid * 8]);
        gl_lds16(sv0, &Vs[bsel][tid * 8]);
        sk0 += 64 * C; sv0 += 64;
    };

    // loop-invariant swizzled read offsets
    int skc0 = (quad ^ m8) << 3;         // K-frag chunk, k-step 0
    int skc1 = ((quad + 4) ^ m8) << 3;   // K-frag chunk, k-step 1
    int vq = quad >> 1, vlo = (quad & 1) * 4;

    auto BODY = [&](int cur, bool last) {   // cur is always a literal
        asm volatile("s_waitcnt vmcnt(0)" ::: "memory");  // own STAGE(cur) done
        __builtin_amdgcn_s_barrier();                     // => tile fully in LDS
        if (!last)
            STAGE(cur ^ 1);
        __builtin_amdgcn_sched_barrier(0);

        // S^T = K·Q^T for BOTH groups; K-frags read once, used twice.
        // Then exp2 -> pack to PV A-frags in-register.
        short4v pa[4], pb[4];
        #pragma unroll
        for (int t = 0; t < 4; ++t) {
            const unsigned short* kr = &Ks[cur][(t * 16 + mr) * 64];
            short8 kf0 = *(const short8*)(kr + skc0);
            short8 kf1 = *(const short8*)(kr + skc1);
            __builtin_amdgcn_s_setprio(1);
            floatx4 ta = {}, tb = {};
            ta = __builtin_amdgcn_mfma_f32_16x16x32_bf16(kf0, qa0, ta, 0, 0, 0);
            ta = __builtin_amdgcn_mfma_f32_16x16x32_bf16(kf1, qa1, ta, 0, 0, 0);
            tb = __builtin_amdgcn_mfma_f32_16x16x32_bf16(kf0, qb0, tb, 0, 0, 0);
            tb = __builtin_amdgcn_mfma_f32_16x16x32_bf16(kf1, qb1, tb, 0, 0, 0);
            __builtin_amdgcn_s_setprio(0);
            float e0, e1, e2, e3, f0, f1, f2, f3;
            asm("v_exp_f32 %0, %1" : "=v"(e0) : "v"(ta[0]));
            asm("v_exp_f32 %0, %1" : "=v"(e1) : "v"(ta[1]));
            asm("v_exp_f32 %0, %1" : "=v"(e2) : "v"(ta[2]));
            asm("v_exp_f32 %0, %1" : "=v"(e3) : "v"(ta[3]));
            asm("v_exp_f32 %0, %1" : "=v"(f0) : "v"(tb[0]));
            asm("v_exp_f32 %0, %1" : "=v"(f1) : "v"(tb[1]));
            asm("v_exp_f32 %0, %1" : "=v"(f2) : "v"(tb[2]));
            asm("v_exp_f32 %0, %1" : "=v"(f3) : "v"(tb[3]));
            unsigned int ua0, ua1, ub0, ub1;
            asm("v_cvt_pk_bf16_f32 %0, %1, %2" : "=v"(ua0) : "v"(e0), "v"(e1));
            asm("v_cvt_pk_bf16_f32 %0, %1, %2" : "=v"(ua1) : "v"(e2), "v"(e3));
            asm("v_cvt_pk_bf16_f32 %0, %1, %2" : "=v"(ub0) : "v"(f0), "v"(f1));
            asm("v_cvt_pk_bf16_f32 %0, %1, %2" : "=v"(ub1) : "v"(f2), "v"(f3));
            union { unsigned int u[2]; short4v s4; } ca, cb;
            ca.u[0] = ua0; ca.u[1] = ua1;
            cb.u[0] = ub0; cb.u[1] = ub1;
            pa[t] = ca.s4;
            pb[t] = cb.s4;
        }

        // O += P·V (16x16x16): V-frags read once, used for both groups.
        __builtin_amdgcn_s_setprio(1);
        #pragma unroll
        for (int t = 0; t < 4; ++t) {
            int vslot = (((2 * t + vq) ^ m8) << 3) + vlo;
            #pragma unroll
            for (int j = 0; j < 4; ++j) {
                short4v vb = *(const short4v*)&Vs[cur][(j * 16 + mr) * 64 + vslot];
                OaccA[j] = __builtin_amdgcn_mfma_f32_16x16x16bf16_1k(
                    pa[t], vb, OaccA[j], 0, 0, 0);
                OaccB[j] = __builtin_amdgcn_mfma_f32_16x16x16bf16_1k(
                    pb[t], vb, OaccB[j], 0, 0, 0);
            }
            la = __builtin_amdgcn_mfma_f32_16x16x16bf16_1k(pa[t], ones, la, 0, 0, 0);
            lb = __builtin_amdgcn_mfma_f32_16x16x16bf16_1k(pb[t], ones, lb, 0, 0, 0);
        }
        __builtin_amdgcn_s_setprio(0);
        __builtin_amdgcn_sched_barrier(0);
    };

    STAGE(0);
    for (int kt2 = 0; kt2 < 15; ++kt2) {
        BODY(0, false);
        BODY(1, false);
    }
    BODY(0, false);
    BODY(1, true);

    // l[r] = sum_k P[q = quad*4 + r][k]  (D-layout row = quad*4+reg)
    float inva[4], invb[4];
    #pragma unroll
    for (int r = 0; r < 4; ++r) {
        inva[r] = 1.0f / la[r];
        invb[r] = 1.0f / lb[r];
    }

    if (pass == 0) {
        #pragma unroll
        for (int t = 0; t < 4; ++t)
            #pragma unroll
            for (int r = 0; r < 4; ++r) {
                int n = qw + quad * 4 + r;
                Out[((size_t)(b * N + n)) * C + h * D + t * 16 + mr] =
                    __float2bfloat16(OaccA[t][r] * inva[r]);
                Out[((size_t)(b * N + n + 128)) * C + h * D + t * 16 + mr] =
                    __float2bfloat16(OaccB[t][r] * invb[r]);
            }
    } else {
        size_t bbase = (size_t)b * N * C;
        #pragma unroll
        for (int t = 0; t < 4; ++t)
            #pragma unroll
            for (int r = 0; r < 4; ++r) {
                int n = qw + quad * 4 + r;
                int c = h * D + t * 16 + mr;
                Out[bbase + (size_t)(c * 4 + (n >> 9)) * 512 + (n & 511)] =
                    __float2bfloat16(OaccA[t][r] * inva[r]);
                int n2 = n + 128;
                Out[bbase + (size_t)(c * 4 + (n2 >> 9)) * 512 + (n2 & 511)] =
                    __float2bfloat16(OaccB[t][r] * invb[r]);
            }
    }
}

// ---------------------------------------------------------------------------
extern "C" void kernel_launch(void* const* d_in, const int* in_sizes, int n_in,
                              void* d_out, int out_size, void* d_ws, size_t ws_size,
                              hipStream_t stream)
{
    const void* x   = d_in[0];
    const void* y   = d_in[1];
    const void* g_r = d_in[10];
    const void* b_r = d_in[11];
    const void* g_d = d_in[12];
    const void* b_d = d_in[13];

    Ptrs ptrs;
    for (int i = 0; i < 18; ++i) ptrs.p[i] = d_in[i];

    const size_t SL = (size_t)B * N * C;  // 4M elements

    char* wsb = (char*)d_ws;
    bf16* q   = (bf16*)wsb;                            // row-major, pre-scaled
    bf16* k   = (bf16*)(wsb + 8ull * 1024 * 1024);     // row-major
    bf16* vrT = (bf16*)(wsb + 16ull * 1024 * 1024);    // transposed [b,c][n]
    bf16* vdT = (bf16*)(wsb + 24ull * 1024 * 1024);    // transposed [b,c][n]
    bf16* xn  = (bf16*)(wsb + 32ull * 1024 * 1024);
    bf16* yn  = (bf16*)(wsb + 40ull * 1024 * 1024);
    bf16* wts = (bf16*)(wsb + 48ull * 1024 * 1024);    // 6 x 512KB bf16 weights
    bf16* Or = xn;   // overlay xn/yn (dead after the staging GEMMs)
    bf16* Ad = yn;

    float* out0 = (float*)d_out;        // final out_r (fp32)
    float* out1 = (float*)d_out + SL;   // final out_d (fp32)

    detect_kernel<<<18, 64, 0, stream>>>(ptrs);
    convert_w<<<dim3(64, 6), 256, 0, stream>>>(ptrs, wts);
    ln_kernel<<<2 * B * N / 4, 256, 0, stream>>>(x, y, g_r, b_r, g_d, b_d, xn, yn);

    gemm_stage<<<dim3(4, 64, 4), 256, 0, stream>>>(xn, yn, wts, ptrs, q, k, vrT, vdT);

    dim3 fg(8, 8, 8);  // both flash passes, 8-wave blocks, 256 q-rows: 512 blocks
    flash_mfma<<<fg, 512, 0, stream>>>(q, k, vrT, vdT, Or, Ad);

    gemm_out<<<dim3(4, 64, 2), 256, 0, stream>>>(Or, Ad, wts, ptrs, out0, out1);
}

// Round 11
// 243.250 us; speedup vs baseline: 1.0947x; 1.0947x over previous
//
#include <hip/hip_runtime.h>
#include <hip/hip_bf16.h>

typedef __hip_bfloat16 bf16;
typedef __attribute__((ext_vector_type(8))) short short8;
typedef __attribute__((ext_vector_type(4))) short short4v;
typedef __attribute__((ext_vector_type(4))) float floatx4;

static constexpr int B = 4;
static constexpr int N = 2048;
static constexpr int C = 512;
static constexpr int H = 8;
static constexpr int D = 64;

// 0.125 * log2(e): folded into q so flash can use native exp2.
#define QK_SCALE 0.18033688011112042f

// Per-input dtype flags: 0 = bf16, 1 = fp32, 2 = all-zero tensor.
__device__ int g_flags[18];

__device__ __forceinline__ float u2f(unsigned short u) {
    return __uint_as_float(((unsigned int)u) << 16);
}
__device__ __forceinline__ unsigned short f2bf(float f) {  // RNE
    unsigned int u = __float_as_uint(f);
    return (unsigned short)((u + 0x7FFFu + ((u >> 16) & 1u)) >> 16);
}
__device__ __forceinline__ float ldin(const void* p, size_t i, int f) {
    if (f == 2) return 0.0f;
    return f ? ((const float*)p)[i] : u2f(((const unsigned short*)p)[i]);
}

// Load 8 consecutive floats starting at element idx, honoring dtype flag.
__device__ __forceinline__ void ld8(const void* p, size_t idx, int f, float* o) {
    if (f == 1) {
        const float4* q = (const float4*)((const float*)p + idx);
        float4 a = q[0], b2 = q[1];
        o[0] = a.x; o[1] = a.y; o[2] = a.z; o[3] = a.w;
        o[4] = b2.x; o[5] = b2.y; o[6] = b2.z; o[7] = b2.w;
    } else if (f == 0) {
        short8 s8 = *(const short8*)((const unsigned short*)p + idx);
        #pragma unroll
        for (int i = 0; i < 8; ++i) o[i] = u2f((unsigned short)s8[i]);
    } else {
        #pragma unroll
        for (int i = 0; i < 8; ++i) o[i] = 0.0f;
    }
}

// Async global->LDS DMA, 16B per lane. LDS dest is wave-uniform base +
// lane*16 (lane0's pointer value is the base).
__device__ __forceinline__ void gl_lds16(const unsigned short* g, unsigned short* l) {
    __builtin_amdgcn_global_load_lds(
        (const __attribute__((address_space(1))) unsigned int*)g,
        (__attribute__((address_space(3))) unsigned int*)l,
        16, 0, 0);
}

struct Ptrs { const void* p[18]; };

__global__ void detect_kernel(Ptrs ptrs) {
    int t = blockIdx.x;
    int lane = threadIdx.x;  // 64
    unsigned int v = ((const unsigned int*)ptrs.p[t])[lane];
    unsigned int e = (v >> 7) & 0xFF;
    unsigned long long mp = __ballot(e >= 96 && e <= 144);
    unsigned long long mz = __ballot(v != 0u);
    if (lane == 0)
        g_flags[t] = (mz == 0ull) ? 2 : ((__popcll(mp) >= 32) ? 0 : 1);
}

// ---------------------------------------------------------------------------
// One-shot weight conversion: all 6 W matrices (512x512) -> bf16 workspace.
// ---------------------------------------------------------------------------
__global__ __launch_bounds__(256) void convert_w(Ptrs ptrs, bf16* dst) {
    int wsel = blockIdx.y;
    int wi = wsel < 4 ? 2 + 2 * wsel : 14 + 2 * (wsel - 4);  // Wq,Wk,Wvr,Wvd,Wpr,Wpd
    int f = g_flags[wi];
    const void* src = ptrs.p[wi];
    unsigned short* out = (unsigned short*)dst + (size_t)wsel * 262144;
    int base = (blockIdx.x * 256 + threadIdx.x) * 16;
    if (f == 1) {
        const float4* s = (const float4*)((const float*)src + base);
        float4 f0 = s[0], f1 = s[1], f2 = s[2], f3 = s[3];
        uint4 o0, o1;
        o0.x = f2bf(f0.x) | ((unsigned int)f2bf(f0.y) << 16);
        o0.y = f2bf(f0.z) | ((unsigned int)f2bf(f0.w) << 16);
        o0.z = f2bf(f1.x) | ((unsigned int)f2bf(f1.y) << 16);
        o0.w = f2bf(f1.z) | ((unsigned int)f2bf(f1.w) << 16);
        o1.x = f2bf(f2.x) | ((unsigned int)f2bf(f2.y) << 16);
        o1.y = f2bf(f2.z) | ((unsigned int)f2bf(f2.w) << 16);
        o1.z = f2bf(f3.x) | ((unsigned int)f2bf(f3.y) << 16);
        o1.w = f2bf(f3.z) | ((unsigned int)f2bf(f3.w) << 16);
        *(uint4*)(out + base) = o0;
        *(uint4*)(out + base + 8) = o1;
    } else if (f == 0) {
        const uint4* s = (const uint4*)((const unsigned short*)src + base);
        uint4 a = s[0], b2 = s[1];
        *(uint4*)(out + base) = a;
        *(uint4*)(out + base + 8) = b2;
    } else {
        uint4 z = {0, 0, 0, 0};
        *(uint4*)(out + base) = z;
        *(uint4*)(out + base + 8) = z;
    }
}

// ---------------------------------------------------------------------------
// LayerNorm v2: ONE WAVE PER ROW. 64 lanes x 8 ch, butterfly shfl reduce,
// no LDS, no barriers, fully vectorized loads/stores. 4 rows per block.
// ---------------------------------------------------------------------------
__global__ __launch_bounds__(256) void ln_kernel(
    const void* __restrict__ x, const void* __restrict__ y,
    const void* __restrict__ g_r, const void* __restrict__ b_r,
    const void* __restrict__ g_d, const void* __restrict__ b_d,
    bf16* __restrict__ xn, bf16* __restrict__ yn)
{
    int tid = threadIdx.x;
    int wid = tid >> 6, lane = tid & 63;
    int row = blockIdx.x * 4 + wid;
    bool isY = row >= B * N;
    int r = isY ? row - B * N : row;
    const void* src = isY ? y : x;
    int sf = isY ? g_flags[1] : g_flags[0];
    const void* g  = isY ? g_d : g_r;
    int gf = isY ? g_flags[12] : g_flags[10];
    const void* bb = isY ? b_d : b_r;
    int bflag = isY ? g_flags[13] : g_flags[11];
    bf16* dst = (isY ? yn : xn) + (size_t)r * C;

    int col = lane * 8;
    float v[8];
    ld8(src, (size_t)r * C + col, sf, v);

    float s = 0.f, sq = 0.f;
    #pragma unroll
    for (int i = 0; i < 8; ++i) { s += v[i]; sq += v[i] * v[i]; }
    #pragma unroll
    for (int off = 1; off < 64; off <<= 1) {
        s  += __shfl_xor(s, off);
        sq += __shfl_xor(sq, off);
    }
    float mu = s * (1.0f / C);
    float var = sq * (1.0f / C) - mu * mu;
    float rs = rsqrtf(var + 1e-5f);

    float gv[8], bv[8];
    ld8(g, col, gf, gv);
    ld8(bb, col, bflag, bv);

    union { unsigned short us[8]; short8 s8; } o;
    #pragma unroll
    for (int i = 0; i < 8; ++i)
        o.us[i] = f2bf((v[i] - mu) * rs * gv[i] + bv[i]);
    *(short8*)(dst + col) = o.s8;
}

// ---------------------------------------------------------------------------
// MFMA GEMM core v5 = v3 K-loop (best measured) + LDS-TRANSPOSE EPILOGUE
// for omode2. The transposed stores (vrT/vdT) previously put adjacent lanes
// 4KB apart -> ~64 memory beats per store instr; the epilogue dominated the
// block (which is why 8 K-loop variants never moved the needle). Now:
// acc -> LDS [o][r] (padded stride 132), barrier, coalesced 16B row stores.
// K-loop: 128x128 tile, 64x64 wave tile, BK=64 windows, double-buffered
// 64KB LDS via global_load_lds, XOR seg swizzle, vmcnt(0) -> barrier ->
// STAGE(next) -> compute.
// omode 0: bf16 row-major; 1: fp32 row-major; 2: bf16 transposed per-batch.
// ---------------------------------------------------------------------------
__device__ __forceinline__ void gemm_core(
    const bf16* __restrict__ A, const bf16* __restrict__ W,
    const void* __restrict__ bias, int bflag, void* __restrict__ Cout,
    int omode, float oscale, int n0, int m0)
{
    // unified LDS: As = SH[buf*8192], Ws = SH[16384 + buf*8192]; the omode2
    // transpose buffer T = SH[0..16895] reuses the A region after the K-loop.
    __shared__ __align__(16) unsigned short SH[4 * 128 * 64];

    int tid = threadIdx.x;
    int wave = tid >> 6, lane = tid & 63;
    int wm = (wave >> 1) * 64, wn = (wave & 1) * 64;
    int quad = lane >> 4, mr = lane & 15;
    int m8 = mr & 7;

    floatx4 acc[4][4] = {};

    // Staging: per window each tile = 128 rows x 8 segs(16B) = 1024 chunks,
    // 4 per thread. LDS slot (row, s) receives global seg s^(row&7).
    const unsigned short* Asrc[4];
    const unsigned short* Wsrc[4];
    #pragma unroll
    for (int i = 0; i < 4; ++i) {
        int c = i * 256 + tid, row = c >> 3, sg = c & 7;
        Asrc[i] = (const unsigned short*)A + (size_t)(m0 + row) * 512 + ((sg ^ (row & 7)) << 3);
        Wsrc[i] = (const unsigned short*)W + (size_t)(n0 + row) * 512 + ((sg ^ (row & 7)) << 3);
    }

    auto STAGE = [&](int w, int bsel) {
        int ko = w * 64;  // shorts; <= 896B -> folds into imm offset
        #pragma unroll
        for (int i = 0; i < 4; ++i) {
            gl_lds16(Asrc[i] + ko, &SH[bsel * 8192 + (i * 256 + tid) * 8]);
            gl_lds16(Wsrc[i] + ko, &SH[16384 + bsel * 8192 + (i * 256 + tid) * 8]);
        }
    };

    auto WBODY = [&](int bsel, int w) {   // bsel, w always literals
        asm volatile("s_waitcnt vmcnt(0)" ::: "memory");  // own STAGE(w) done
        __builtin_amdgcn_s_barrier();                     // => ALL staging done
        if (w < 7)
            STAGE(w + 1, bsel ^ 1);
        __builtin_amdgcn_sched_barrier(0);

        #pragma unroll
        for (int kk = 0; kk < 2; ++kk) {
            int sl = ((kk * 4 + quad) ^ m8) << 3;
            short8 af[4], bfr[4];
            #pragma unroll
            for (int i = 0; i < 4; ++i)
                af[i] = *(const short8*)&SH[bsel * 8192 + (wm + i * 16 + mr) * 64 + sl];
            #pragma unroll
            for (int j = 0; j < 4; ++j)
                bfr[j] = *(const short8*)&SH[16384 + bsel * 8192 + (wn + j * 16 + mr) * 64 + sl];
            #pragma unroll
            for (int i = 0; i < 4; ++i)
                #pragma unroll
                for (int j = 0; j < 4; ++j)
                    acc[i][j] = __builtin_amdgcn_mfma_f32_16x16x32_bf16(
                        af[i], bfr[j], acc[i][j], 0, 0, 0);
        }
        __builtin_amdgcn_sched_barrier(0);
    };

    STAGE(0, 0);
    #pragma unroll
    for (int g = 0; g < 4; ++g) {
        WBODY(0, 2 * g);
        WBODY(1, 2 * g + 1);
    }

    float bv[4];
    #pragma unroll
    for (int j = 0; j < 4; ++j)
        bv[j] = ldin(bias, n0 + wn + j * 16 + mr, bflag);

    if (omode == 2) {
        // ---- LDS-transpose epilogue: coalesced transposed stores ----
        constexpr int TP = 132;  // padded stride (shorts): bank-spread, 8B-aligned
        __builtin_amdgcn_s_barrier();   // all waves done with K-loop LDS reads
        #pragma unroll
        for (int i = 0; i < 4; ++i) {
            #pragma unroll
            for (int j = 0; j < 4; ++j) {
                int o_l = wn + j * 16 + mr;
                int r_l = wm + i * 16 + quad * 4;
                union { unsigned short s[4]; uint2 u2; } pk;
                #pragma unroll
                for (int reg = 0; reg < 4; ++reg)
                    pk.s[reg] = f2bf((acc[i][j][reg] + bv[j]) * oscale);
                *(uint2*)&SH[o_l * TP + r_l] = pk.u2;
            }
        }
        __builtin_amdgcn_s_barrier();
        // read back row-wise, store contiguous 128B per (o-row, half)
        int o_l = tid >> 1, seg = tid & 1;
        int batch = m0 >> 11, nbase = m0 & 2047;
        bf16* dst = (bf16*)Cout + ((size_t)(batch * 512 + n0 + o_l)) * 2048
                  + nbase + seg * 64;
        #pragma unroll
        for (int k2 = 0; k2 < 8; ++k2) {
            uint4 vv = *(uint4*)&SH[o_l * TP + seg * 64 + k2 * 8];
            *(uint4*)(dst + k2 * 8) = vv;
        }
        return;
    }

    #pragma unroll
    for (int i = 0; i < 4; ++i) {
        #pragma unroll
        for (int j = 0; j < 4; ++j) {
            int o = n0 + wn + j * 16 + mr;
            #pragma unroll
            for (int reg = 0; reg < 4; ++reg) {
                int r = m0 + wm + i * 16 + quad * 4 + reg;
                float val = (acc[i][j][reg] + bv[j]) * oscale;
                if (omode == 0) {
                    ((bf16*)Cout)[(size_t)r * 512 + o] = __float2bfloat16(val);
                } else {
                    ((float*)Cout)[(size_t)r * 512 + o] = val;
                }
            }
        }
    }
}

// XCD decode for grid (4, 64, z): linear id = bx + 4*by (+256*z) -> XCD =
// id&7. Give each XCD a contiguous band of 8 m-panels (all 4 n-tiles each):
// A working set 1MB/XCD (L2-fits), W 0.5MB.
__device__ __forceinline__ void swz_nm(int& n0, int& m0) {
    int lid = blockIdx.x + 4 * blockIdx.y;   // 0..255 within z-slab
    int xcd = lid & 7;
    int grp = lid >> 3;                      // 0..31
    m0 = (xcd * 8 + (grp >> 2)) * 128;
    n0 = (grp & 3) * 128;
}

// 4 staging GEMMs in one dispatch: z = {q, k, vrT, vdT}
__global__ __launch_bounds__(256, 2) void gemm_stage(
    const bf16* __restrict__ xn, const bf16* __restrict__ yn,
    const bf16* __restrict__ wts, Ptrs ptrs,
    bf16* __restrict__ q, bf16* __restrict__ k,
    bf16* __restrict__ vrT, bf16* __restrict__ vdT)
{
    int z = blockIdx.z;
    const bf16* A = (z == 0) ? yn : xn;
    const bf16* W = wts + (size_t)z * 262144;
    int bi = 3 + 2 * z;
    void* Cout = (z == 0) ? (void*)q : (z == 1) ? (void*)k
               : (z == 2) ? (void*)vrT : (void*)vdT;
    int omode = (z < 2) ? 0 : 2;
    float oscale = (z == 0) ? QK_SCALE : 1.0f;
    int n0, m0;
    swz_nm(n0, m0);
    gemm_core(A, W, ptrs.p[bi], g_flags[bi], Cout, omode, oscale, n0, m0);
}

// 2 output projections in one dispatch
__global__ __launch_bounds__(256, 2) void gemm_out(
    const bf16* __restrict__ Or, const bf16* __restrict__ Ad,
    const bf16* __restrict__ wts, Ptrs ptrs,
    float* __restrict__ out0, float* __restrict__ out1)
{
    int z = blockIdx.z;
    const bf16* A = z ? Ad : Or;
    const bf16* W = wts + (size_t)(4 + z) * 262144;
    int bi = 15 + 2 * z;
    int n0, m0;
    swz_nm(n0, m0);
    gemm_core(A, W, ptrs.p[bi], g_flags[bi], z ? (void*)out1 : (void*)out0,
              1, 1.0f, n0, m0);
}

// ---------------------------------------------------------------------------
// MFMA flash attention v7 (UNCHANGED from R9): 32 Q-rows per wave (two
// 16-row groups sharing every K/V fragment read). 8-wave blocks, 256
// q-rows/block, grid 512 (2 blocks/CU). Swapped-QK^T; P in registers;
// row-sums via ones-MFMA. vmcnt(0) -> barrier -> STAGE(next) -> compute.
// ---------------------------------------------------------------------------
__global__ __launch_bounds__(512, 4) void flash_mfma(
    const bf16* __restrict__ qm, const bf16* __restrict__ km,
    const bf16* __restrict__ vrT, const bf16* __restrict__ vdT,
    bf16* __restrict__ Or, bf16* __restrict__ Ad)
{
    __shared__ __align__(16) unsigned short Ks[2][64 * 64];
    __shared__ __align__(16) unsigned short Vs[2][64 * 64];   // V^T tile [d][kcol]

    // bijective swizzle: phys = [grp:3][qblk:3][xcd:3] -> group = grp<<3|xcd
    int phys = blockIdx.x + 8 * blockIdx.y + 64 * blockIdx.z;
    int s = phys >> 3;
    int qblk = s & 7;
    int gidx = (phys & 7) | ((s >> 3) << 3);
    int pass = gidx >> 5;
    int b = (gidx >> 3) & 3;
    int h = gidx & 7;

    const bf16* Q  = pass ? km : qm;
    const bf16* K  = pass ? qm : km;
    const bf16* Vt = pass ? vdT : vrT;
    bf16* Out = pass ? Ad : Or;

    int tid = threadIdx.x;
    int wave = tid >> 6, lane = tid & 63;
    int quad = lane >> 4, mr = lane & 15;
    int m8 = mr & 7;
    int qw = qblk * 256 + wave * 16;   // group 0; group 1 = qw + 128

    // Q fragments for both row groups: B-operand (n=q-row=mr, c=quad*8+j)
    const unsigned short* Qb0 = (const unsigned short*)Q + ((size_t)(b * N + qw + mr)) * C + h * D;
    const unsigned short* Qb1 = Qb0 + (size_t)128 * C;
    short8 qa0 = *(const short8*)(Qb0 + quad * 8);
    short8 qa1 = *(const short8*)(Qb0 + 32 + quad * 8);
    short8 qb0 = *(const short8*)(Qb1 + quad * 8);
    short8 qb1 = *(const short8*)(Qb1 + 32 + quad * 8);

    floatx4 OaccA[4] = {};
    floatx4 OaccB[4] = {};
    floatx4 la = {}, lb = {};

    short4v ones;
    {
        union { unsigned int u[2]; short4v s4; } cv;
        cv.u[0] = 0x3F803F80u; cv.u[1] = 0x3F803F80u;  // 4x bf16 1.0
        ones = cv.s4;
    }

    // DMA staging: 512 chunks (16B) per tile per array; 1 K + 1 V per thread.
    // LDS slot (row, cs) holds data chunk (row, cs ^ (row&7)).
    int r0 = tid >> 3, cs0 = tid & 7;
    const unsigned short* Kb  = (const unsigned short*)K + ((size_t)b * N) * C + h * D;
    const unsigned short* Vtb = (const unsigned short*)Vt + ((size_t)(b * 512 + h * 64)) * 2048;
    const unsigned short* sk0 = Kb + (size_t)r0 * C + ((cs0 ^ (r0 & 7)) << 3);
    const unsigned short* sv0 = Vtb + (size_t)r0 * 2048 + ((cs0 ^ (r0 & 7)) << 3);

    auto STAGE = [&](int bsel) {
        gl_lds16(sk0, &Ks[bsel][tid * 8]);
        gl_lds16(sv0, &Vs[bsel][tid * 8]);
        sk0 += 64 * C; sv0 += 64;
    };

    // loop-invariant swizzled read offsets
    int skc0 = (quad ^ m8) << 3;         // K-frag chunk, k-step 0
    int skc1 = ((quad + 4) ^ m8) << 3;   // K-frag chunk, k-step 1
    int vq = quad >> 1, vlo = (quad & 1) * 4;

    auto BODY = [&](int cur, bool last) {   // cur is always a literal
        asm volatile("s_waitcnt vmcnt(0)" ::: "memory");  // own STAGE(cur) done
        __builtin_amdgcn_s_barrier();                     // => tile fully in LDS
        if (!last)
            STAGE(cur ^ 1);
        __builtin_amdgcn_sched_barrier(0);

        // S^T = K·Q^T for BOTH groups; K-frags read once, used twice.
        // Then exp2 -> pack to PV A-frags in-register.
        short4v pa[4], pb[4];
        #pragma unroll
        for (int t = 0; t < 4; ++t) {
            const unsigned short* kr = &Ks[cur][(t * 16 + mr) * 64];
            short8 kf0 = *(const short8*)(kr + skc0);
            short8 kf1 = *(const short8*)(kr + skc1);
            __builtin_amdgcn_s_setprio(1);
            floatx4 ta = {}, tb = {};
            ta = __builtin_amdgcn_mfma_f32_16x16x32_bf16(kf0, qa0, ta, 0, 0, 0);
            ta = __builtin_amdgcn_mfma_f32_16x16x32_bf16(kf1, qa1, ta, 0, 0, 0);
            tb = __builtin_amdgcn_mfma_f32_16x16x32_bf16(kf0, qb0, tb, 0, 0, 0);
            tb = __builtin_amdgcn_mfma_f32_16x16x32_bf16(kf1, qb1, tb, 0, 0, 0);
            __builtin_amdgcn_s_setprio(0);
            float e0, e1, e2, e3, f0, f1, f2, f3;
            asm("v_exp_f32 %0, %1" : "=v"(e0) : "v"(ta[0]));
            asm("v_exp_f32 %0, %1" : "=v"(e1) : "v"(ta[1]));
            asm("v_exp_f32 %0, %1" : "=v"(e2) : "v"(ta[2]));
            asm("v_exp_f32 %0, %1" : "=v"(e3) : "v"(ta[3]));
            asm("v_exp_f32 %0, %1" : "=v"(f0) : "v"(tb[0]));
            asm("v_exp_f32 %0, %1" : "=v"(f1) : "v"(tb[1]));
            asm("v_exp_f32 %0, %1" : "=v"(f2) : "v"(tb[2]));
            asm("v_exp_f32 %0, %1" : "=v"(f3) : "v"(tb[3]));
            unsigned int ua0, ua1, ub0, ub1;
            asm("v_cvt_pk_bf16_f32 %0, %1, %2" : "=v"(ua0) : "v"(e0), "v"(e1));
            asm("v_cvt_pk_bf16_f32 %0, %1, %2" : "=v"(ua1) : "v"(e2), "v"(e3));
            asm("v_cvt_pk_bf16_f32 %0, %1, %2" : "=v"(ub0) : "v"(f0), "v"(f1));
            asm("v_cvt_pk_bf16_f32 %0, %1, %2" : "=v"(ub1) : "v"(f2), "v"(f3));
            union { unsigned int u[2]; short4v s4; } ca, cb;
            ca.u[0] = ua0; ca.u[1] = ua1;
            cb.u[0] = ub0; cb.u[1] = ub1;
            pa[t] = ca.s4;
            pb[t] = cb.s4;
        }

        // O += P·V (16x16x16): V-frags read once, used for both groups.
        __builtin_amdgcn_s_setprio(1);
        #pragma unroll
        for (int t = 0; t < 4; ++t) {
            int vslot = (((2 * t + vq) ^ m8) << 3) + vlo;
            #pragma unroll
            for (int j = 0; j < 4; ++j) {
                short4v vb = *(const short4v*)&Vs[cur][(j * 16 + mr) * 64 + vslot];
                OaccA[j] = __builtin_amdgcn_mfma_f32_16x16x16bf16_1k(
                    pa[t], vb, OaccA[j], 0, 0, 0);
                OaccB[j] = __builtin_amdgcn_mfma_f32_16x16x16bf16_1k(
                    pb[t], vb, OaccB[j], 0, 0, 0);
            }
            la = __builtin_amdgcn_mfma_f32_16x16x16bf16_1k(pa[t], ones, la, 0, 0, 0);
            lb = __builtin_amdgcn_mfma_f32_16x16x16bf16_1k(pb[t], ones, lb, 0, 0, 0);
        }
        __builtin_amdgcn_s_setprio(0);
        __builtin_amdgcn_sched_barrier(0);
    };

    STAGE(0);
    for (int kt2 = 0; kt2 < 15; ++kt2) {
        BODY(0, false);
        BODY(1, false);
    }
    BODY(0, false);
    BODY(1, true);

    // l[r] = sum_k P[q = quad*4 + r][k]  (D-layout row = quad*4+reg)
    float inva[4], invb[4];
    #pragma unroll
    for (int r = 0; r < 4; ++r) {
        inva[r] = 1.0f / la[r];
        invb[r] = 1.0f / lb[r];
    }

    if (pass == 0) {
        #pragma unroll
        for (int t = 0; t < 4; ++t)
            #pragma unroll
            for (int r = 0; r < 4; ++r) {
                int n = qw + quad * 4 + r;
                Out[((size_t)(b * N + n)) * C + h * D + t * 16 + mr] =
                    __float2bfloat16(OaccA[t][r] * inva[r]);
                Out[((size_t)(b * N + n + 128)) * C + h * D + t * 16 + mr] =
                    __float2bfloat16(OaccB[t][r] * invb[r]);
            }
    } else {
        size_t bbase = (size_t)b * N * C;
        #pragma unroll
        for (int t = 0; t < 4; ++t)
            #pragma unroll
            for (int r = 0; r < 4; ++r) {
                int n = qw + quad * 4 + r;
                int c = h * D + t * 16 + mr;
                Out[bbase + (size_t)(c * 4 + (n >> 9)) * 512 + (n & 511)] =
                    __float2bfloat16(OaccA[t][r] * inva[r]);
                int n2 = n + 128;
                Out[bbase + (size_t)(c * 4 + (n2 >> 9)) * 512 + (n2 & 511)] =
                    __float2bfloat16(OaccB[t][r] * invb[r]);
            }
    }
}

// ---------------------------------------------------------------------------
extern "C" void kernel_launch(void* const* d_in, const int* in_sizes, int n_in,
                              void* d_out, int out_size, void* d_ws, size_t ws_size,
                              hipStream_t stream)
{
    const void* x   = d_in[0];
    const void* y   = d_in[1];
    const void* g_r = d_in[10];
    const void* b_r = d_in[11];
    const void* g_d = d_in[12];
    const void* b_d = d_in[13];

    Ptrs ptrs;
    for (int i = 0; i < 18; ++i) ptrs.p[i] = d_in[i];

    const size_t SL = (size_t)B * N * C;  // 4M elements

    char* wsb = (char*)d_ws;
    bf16* q   = (bf16*)wsb;                            // row-major, pre-scaled
    bf16* k   = (bf16*)(wsb + 8ull * 1024 * 1024);     // row-major
    bf16* vrT = (bf16*)(wsb + 16ull * 1024 * 1024);    // transposed [b,c][n]
    bf16* vdT = (bf16*)(wsb + 24ull * 1024 * 1024);    // transposed [b,c][n]
    bf16* xn  = (bf16*)(wsb + 32ull * 1024 * 1024);
    bf16* yn  = (bf16*)(wsb + 40ull * 1024 * 1024);
    bf16* wts = (bf16*)(wsb + 48ull * 1024 * 1024);    // 6 x 512KB bf16 weights
    bf16* Or = xn;   // overlay xn/yn (dead after the staging GEMMs)
    bf16* Ad = yn;

    float* out0 = (float*)d_out;        // final out_r (fp32)
    float* out1 = (float*)d_out + SL;   // final out_d (fp32)

    detect_kernel<<<18, 64, 0, stream>>>(ptrs);
    convert_w<<<dim3(64, 6), 256, 0, stream>>>(ptrs, wts);
    ln_kernel<<<2 * B * N / 4, 256, 0, stream>>>(x, y, g_r, b_r, g_d, b_d, xn, yn);

    gemm_stage<<<dim3(4, 64, 4), 256, 0, stream>>>(xn, yn, wts, ptrs, q, k, vrT, vdT);

    dim3 fg(8, 8, 8);  // both flash passes, 8-wave blocks, 256 q-rows: 512 blocks
    flash_mfma<<<fg, 512, 0, stream>>>(q, k, vrT, vdT, Or, Ad);

    gemm_out<<<dim3(4, 64, 2), 256, 0, stream>>>(Or, Ad, wts, ptrs, out0, out1);
}